// Round 4
// baseline (301.897 us; speedup 1.0000x reference)
//
#include <hip/hip_runtime.h>
#include <hip/hip_fp16.h>

// adj[b] = tanh(relu(E_b @ E_b^T)) + 0.5*I  -- adj is SYMMETRIC.
// R10: upper-triangle launch. Only super-tiles (r, c2) with r <= 2*c2+1 are
// dispatched (305/batch vs 561). Each off-diagonal 64x64 sub-tile computes
// TWO accumulators from the same LDS fragments:
//   acc  = mfma(bfrag, afrag)  -> (ti,tj) tile, row-major float4 stores
//   accT = mfma(afrag, bfrag)  -> (tj,ti) mirror tile, also float4 stores
// (~80 extra MFMA cyc/wave, zero extra ds_reads). tanh math is per stored
// element (unchanged); staging + launches + barriers HALVE.
// Sub-tile rules: tjn>ti: store direct+mirror; tjn==ti: direct only (diag);
// tjn<ti (only when r==2c2+1, n=0): skip entirely (covered as another WG's
// mirror). Direct/mirror store geometry both 16 rows x 64 B per instr.

#define B_BATCH   16
#define N_SPATIAL 2048
#define T_TEMP    64
#define M_NODES   2112     // 33 * 64
#define D_FEAT    64
#define TILE      64
#define LDSK      72       // fp16 k-stride (+8 pad)

// triangular WG layout per batch: c2=0..15 -> 2*c2+2 strips; c2=16 -> 33
#define WGS_PER_BATCH 305
#define TRI_BASE      272                          // start of c2==16 block
#define TOTAL_WGS     (WGS_PER_BATCH * B_BATCH)    // 4880 = 8 * 610
#define WGS_PER_XCD   (TOTAL_WGS / 8)              // 610 = 2 batches

typedef _Float16 f16x8 __attribute__((ext_vector_type(8)));
typedef float    f32x4 __attribute__((ext_vector_type(4)));

__device__ __forceinline__ f16x8 cvt2(const float4* p) {
    float4 a = p[0], c = p[1];
    f16x8 h;
    h[0] = (_Float16)a.x; h[1] = (_Float16)a.y;
    h[2] = (_Float16)a.z; h[3] = (_Float16)a.w;
    h[4] = (_Float16)c.x; h[5] = (_Float16)c.y;
    h[6] = (_Float16)c.z; h[7] = (_Float16)c.w;
    return h;
}

__device__ __forceinline__ float tanh_relu(float x) {
    x = fmaxf(x, 0.f);
    // tanh(x), x>=0: 1 - 2/(e^{2x}+1); exp->inf saturates to 1
    float e = __expf(2.f * x);
    return 1.f - 2.f * __builtin_amdgcn_rcpf(e + 1.f);
}

__global__ __launch_bounds__(256, 4)
void gram_tanh_mfma(const float* __restrict__ sp,
                    const float* __restrict__ tp,
                    float* __restrict__ out)
{
    // ---- XCD-aware decode: XCD k owns batches 2k,2k+1 (610 WGs each) ----
    const int lin = blockIdx.x;
    const int xcd = lin & 7;
    const int l   = lin >> 3;                 // 0..609
    const int bo  = (l >= WGS_PER_BATCH) ? 1 : 0;
    const int t   = l - bo * WGS_PER_BATCH;   // 0..304
    const int b   = 2 * xcd + bo;

    // ---- triangular decode: t -> (c2, r) with r <= 2*c2+1 ----
    int c2, r;
    if (t >= TRI_BASE) { c2 = 16; r = t - TRI_BASE; }           // r = 0..32
    else {
        c2 = (int)(0.5f * (sqrtf((float)(4 * t + 1)) - 1.f));   // ~floor soln
        while ((c2 + 1) * (c2 + 2) <= t) ++c2;                  // fixups
        while (c2 * (c2 + 1) > t) --c2;
        r = t - c2 * (c2 + 1);                                  // 0..2*c2+1
    }
    const int ti  = r;
    const int tj0 = 2 * c2;
    const bool have2 = (tj0 + 1 < 33);
    const int tj1 = have2 ? tj0 + 1 : 32;
    const bool do0 = (tj0 >= ti);             // else covered by mirror of (tj0,ti)

    __shared__ __align__(16) _Float16 As[TILE][LDSK];       //  9216 B
    __shared__ __align__(16) _Float16 Bs[2][TILE][LDSK];    // 18432 B -> 27648 B

    const int tid = threadIdx.x;

    // ---- stage + convert fp32 -> fp16: row = tid>>2, 16 consecutive k ----
    {
        const int row = tid >> 2;
        const int kb  = (tid & 3) * 16;
        const float* srcA = (ti < 32)
            ? sp + ((size_t)b * N_SPATIAL + (size_t)ti * TILE) * D_FEAT
            : tp + (size_t)b * T_TEMP * D_FEAT;
        const float4* pa = (const float4*)(srcA + (size_t)row * D_FEAT + kb);
        *(f16x8*)&As[row][kb]     = cvt2(pa);
        *(f16x8*)&As[row][kb + 8] = cvt2(pa + 2);

        if (do0) {
            const float* srcB0 = (tj0 < 32)
                ? sp + ((size_t)b * N_SPATIAL + (size_t)tj0 * TILE) * D_FEAT
                : tp + (size_t)b * T_TEMP * D_FEAT;
            const float4* pb0 = (const float4*)(srcB0 + (size_t)row * D_FEAT + kb);
            *(f16x8*)&Bs[0][row][kb]     = cvt2(pb0);
            *(f16x8*)&Bs[0][row][kb + 8] = cvt2(pb0 + 2);
        }
        if (have2) {
            const float* srcB1 = (tj1 < 32)
                ? sp + ((size_t)b * N_SPATIAL + (size_t)tj1 * TILE) * D_FEAT
                : tp + (size_t)b * T_TEMP * D_FEAT;
            const float4* pb1 = (const float4*)(srcB1 + (size_t)row * D_FEAT + kb);
            *(f16x8*)&Bs[1][row][kb]     = cvt2(pb1);
            *(f16x8*)&Bs[1][row][kb + 8] = cvt2(pb1 + 2);
        }
    }
    __syncthreads();   // the ONLY barrier

    const int wave = tid >> 6;
    const int lane = tid & 63;
    const int lr   = lane & 15;
    const int q    = lane >> 4;

    float* const outb = out + (size_t)b * M_NODES * M_NODES;

    #pragma unroll
    for (int n = 0; n < 2; ++n) {
        if (n == 0 && !do0) continue;             // WG-uniform skips
        if (n == 1 && !have2) continue;
        const int tjn = n ? tj1 : tj0;
        const bool mirror = (tjn > ti);
        const bool diagT  = (tjn == ti);

        f32x4 acc[4], accT[4];
        #pragma unroll
        for (int tt = 0; tt < 4; ++tt) {
            acc[tt]  = (f32x4){0.f, 0.f, 0.f, 0.f};
            accT[tt] = (f32x4){0.f, 0.f, 0.f, 0.f};
        }

        #pragma unroll
        for (int s = 0; s < 2; ++s) {             // K = 64 = 2 x 32
            f16x8 afrag = *(const f16x8*)&As[wave * 16 + lr][s * 32 + q * 8];
            #pragma unroll
            for (int tt = 0; tt < 4; ++tt) {
                f16x8 bfrag = *(const f16x8*)&Bs[n][tt * 16 + lr][s * 32 + q * 8];
                // direct tile (ti,tjn): swapped operands -> row-major layout
                acc[tt] = __builtin_amdgcn_mfma_f32_16x16x32_f16(bfrag, afrag, acc[tt], 0, 0, 0);
                // mirror tile (tjn,ti): normal operands, same fragments
                if (mirror)
                    accT[tt] = __builtin_amdgcn_mfma_f32_16x16x32_f16(afrag, bfrag, accT[tt], 0, 0, 0);
            }
        }

        // ---- direct store: value C[ti*64+wave*16+lr][tjn*64+tt*16+q*4+i] ----
        {
            const int r_loc = wave * 16 + lr;
            float* dst = outb + (size_t)(ti * TILE + r_loc) * M_NODES
                              + (size_t)(tjn * TILE + q * 4);
            #pragma unroll
            for (int tt = 0; tt < 4; ++tt) {
                const int c_loc = tt * 16 + q * 4;
                float4 o;
                float* po = &o.x;
                #pragma unroll
                for (int i = 0; i < 4; ++i) {
                    float v = tanh_relu(acc[tt][i]);
                    if (diagT && (r_loc == c_loc + i)) v += 0.5f;
                    po[i] = v;
                }
                *(float4*)(dst + tt * 16) = o;
            }
        }

        // ---- mirror store: accT[tt][i] -> out[tjn*64+tt*16+lr][ti*64+wave*16+q*4+i] ----
        if (mirror) {
            const size_t cb = (size_t)(ti * TILE + wave * 16 + q * 4);
            #pragma unroll
            for (int tt = 0; tt < 4; ++tt) {
                float* dstT = outb + (size_t)(tjn * TILE + tt * 16 + lr) * M_NODES + cb;
                float4 o;
                float* po = &o.x;
                #pragma unroll
                for (int i = 0; i < 4; ++i) po[i] = tanh_relu(accT[tt][i]);
                *(float4*)dstT = o;
            }
        }
    }
}

extern "C" void kernel_launch(void* const* d_in, const int* in_sizes, int n_in,
                              void* d_out, int out_size, void* d_ws, size_t ws_size,
                              hipStream_t stream) {
    const float* sp = (const float*)d_in[0];   // [16, 2048, 64] fp32
    const float* tp = (const float*)d_in[1];   // [16, 64, 64]   fp32
    float* out = (float*)d_out;                // [16, 2112, 2112] fp32

    dim3 grid(TOTAL_WGS);                      // 4880; kernel does XCD+tri decode
    dim3 block(256);
    hipLaunchKernelGGL(gram_tanh_mfma, grid, block, 0, stream, sp, tp, out);
}

// Round 5
// 301.830 us; speedup vs baseline: 1.0002x; 1.0002x over previous
//
#include <hip/hip_runtime.h>
#include <hip/hip_fp16.h>

// adj[b] = tanh(relu(E_b @ E_b^T)) + 0.5*I
// E_b = concat(spatial[b] (2048x64), temporal[b] (64x64)) fp32 -> fp16 MFMA,
// fp32 accumulate. Output: [16, 2112, 2112] fp32.
// R11: PERSISTENT workgroups. 768 WGs (= 256 CU x 3, fully co-resident),
// XCD k (lin&7) owns batches 2k,2k+1 = 1122 tiles of 64x128; its 96 WGs
// grid-stride those tiles (11-12 each). Per tile iteration:
//   syncthreads -> regs(fp32)->LDS(fp16) -> syncthreads
//   -> ISSUE next tile's 12 global_load_dwordx4 into regs (T14 issue-early:
//      latency hides under MFMA+epilogue) -> MFMA -> tanh -> float4 stores.
// Removes 8976 short-WG launch/teardown + cold-start stalls (R6..R10 all
// paid full load latency + drain per 64x128 tile). launch_bounds back to
// (256,3): every (256,4) variant regressed vs R6 (VGPR-cap suspicion).
// Epilogue = R9's validated swapped-operand direct-acc float4 stores.
// R10 symmetry dropped (measured neutral; staging is not the bottleneck).

#define B_BATCH   16
#define N_SPATIAL 2048
#define T_TEMP    64
#define M_NODES   2112     // 33 * 64
#define D_FEAT    64
#define TILE      64
#define LDSK      72       // fp16 k-stride (+8 pad)

#define GROUPS_PER_STRIP 17
#define TILES_PER_BATCH  (33 * GROUPS_PER_STRIP)   // 561
#define TILES_PER_XCD    (2 * TILES_PER_BATCH)     // 1122
#define WGS_PER_XCD      96
#define TOTAL_WGS        (WGS_PER_XCD * 8)         // 768 = 3 per CU

typedef _Float16 f16x8 __attribute__((ext_vector_type(8)));
typedef float    f32x4 __attribute__((ext_vector_type(4)));

__device__ __forceinline__ f16x8 cvt2v(float4 a, float4 c) {
    f16x8 h;
    h[0] = (_Float16)a.x; h[1] = (_Float16)a.y;
    h[2] = (_Float16)a.z; h[3] = (_Float16)a.w;
    h[4] = (_Float16)c.x; h[5] = (_Float16)c.y;
    h[6] = (_Float16)c.z; h[7] = (_Float16)c.w;
    return h;
}

__device__ __forceinline__ float tanh_relu(float x) {
    x = fmaxf(x, 0.f);
    // tanh(x), x>=0: 1 - 2/(e^{2x}+1); exp->inf saturates to 1
    float e = __expf(2.f * x);
    return 1.f - 2.f * __builtin_amdgcn_rcpf(e + 1.f);
}

// tile index t (0..1121) -> per-thread staging pointers (row/kb fixed)
__device__ __forceinline__ void tile_ptrs(int t, int xcd, int row, int kb,
                                          const float* __restrict__ sp,
                                          const float* __restrict__ tp,
                                          const float4*& pa,
                                          const float4*& pb0,
                                          const float4*& pb1)
{
    const int bo  = (t >= TILES_PER_BATCH) ? 1 : 0;
    const int rr  = t - bo * TILES_PER_BATCH;
    const int ti  = rr / GROUPS_PER_STRIP;          // 0..32
    const int g   = rr - ti * GROUPS_PER_STRIP;     // 0..16
    const int b   = 2 * xcd + bo;
    const int tj0 = 2 * g;
    const int tj1 = (tj0 + 1 < 33) ? tj0 + 1 : 32;  // clamp (dup on g==16)
    const float* srcA = (ti < 32)
        ? sp + ((size_t)b * N_SPATIAL + (size_t)ti * TILE) * D_FEAT
        : tp + (size_t)b * T_TEMP * D_FEAT;
    const float* srcB0 = (tj0 < 32)
        ? sp + ((size_t)b * N_SPATIAL + (size_t)tj0 * TILE) * D_FEAT
        : tp + (size_t)b * T_TEMP * D_FEAT;
    const float* srcB1 = (tj1 < 32)
        ? sp + ((size_t)b * N_SPATIAL + (size_t)tj1 * TILE) * D_FEAT
        : tp + (size_t)b * T_TEMP * D_FEAT;
    pa  = (const float4*)(srcA  + (size_t)row * D_FEAT + kb);
    pb0 = (const float4*)(srcB0 + (size_t)row * D_FEAT + kb);
    pb1 = (const float4*)(srcB1 + (size_t)row * D_FEAT + kb);
}

__global__ __launch_bounds__(256, 3)
void gram_tanh_mfma(const float* __restrict__ sp,
                    const float* __restrict__ tp,
                    float* __restrict__ out)
{
    const int lin = blockIdx.x;
    const int xcd = lin & 7;                 // round-robin XCD dispatch
    const int w   = lin >> 3;                // 0..95 within XCD

    __shared__ __align__(16) _Float16 As[TILE][LDSK];       //  9216 B
    __shared__ __align__(16) _Float16 Bs[2][TILE][LDSK];    // 18432 B -> 27648 B

    const int tid  = threadIdx.x;
    const int row  = tid >> 2;               // staging row 0..63
    const int kb   = (tid & 3) * 16;         // staging k base
    const int wave = tid >> 6;
    const int lane = tid & 63;
    const int lr   = lane & 15;              // output row within 16-slice
    const int q    = lane >> 4;              // output col quad

    // ---- prologue: prefetch tile w into registers ----
    int t = w;
    float4 ra[4], rb0[4], rb1[4];
    {
        const float4 *pa, *pb0, *pb1;
        tile_ptrs(t, xcd, row, kb, sp, tp, pa, pb0, pb1);
        #pragma unroll
        for (int i = 0; i < 4; ++i) { ra[i] = pa[i]; rb0[i] = pb0[i]; rb1[i] = pb1[i]; }
    }

    for (;;) {
        // ---- decode current tile for compute ----
        const int bo  = (t >= TILES_PER_BATCH) ? 1 : 0;
        const int rr  = t - bo * TILES_PER_BATCH;
        const int ti  = rr / GROUPS_PER_STRIP;
        const int g   = rr - ti * GROUPS_PER_STRIP;
        const int b   = 2 * xcd + bo;
        const int tj0 = 2 * g;
        const bool have2 = (tj0 + 1 < 33);
        const int tj1 = have2 ? tj0 + 1 : 32;

        // ---- regs -> LDS (convert fp32->fp16) ----
        __syncthreads();                     // prev iter's LDS readers done
        *(f16x8*)&As[row][kb]        = cvt2v(ra[0],  ra[1]);
        *(f16x8*)&As[row][kb + 8]    = cvt2v(ra[2],  ra[3]);
        *(f16x8*)&Bs[0][row][kb]     = cvt2v(rb0[0], rb0[1]);
        *(f16x8*)&Bs[0][row][kb + 8] = cvt2v(rb0[2], rb0[3]);
        *(f16x8*)&Bs[1][row][kb]     = cvt2v(rb1[0], rb1[1]);
        *(f16x8*)&Bs[1][row][kb + 8] = cvt2v(rb1[2], rb1[3]);
        __syncthreads();

        // ---- issue NEXT tile's loads now; latency hides under MFMA+epilogue
        const int tn = t + WGS_PER_XCD;
        const bool more = (tn < TILES_PER_XCD);
        if (more) {
            const float4 *pa, *pb0, *pb1;
            tile_ptrs(tn, xcd, row, kb, sp, tp, pa, pb0, pb1);
            #pragma unroll
            for (int i = 0; i < 4; ++i) { ra[i] = pa[i]; rb0[i] = pb0[i]; rb1[i] = pb1[i]; }
        }

        // ---- MFMA (swapped operands -> row-major C layout in acc) ----
        f32x4 acc[2][4];
        #pragma unroll
        for (int n = 0; n < 2; ++n)
            #pragma unroll
            for (int tt = 0; tt < 4; ++tt) acc[n][tt] = (f32x4){0.f, 0.f, 0.f, 0.f};

        #pragma unroll
        for (int s = 0; s < 2; ++s) {        // K = 64 = 2 x 32
            f16x8 afrag = *(const f16x8*)&As[wave * 16 + lr][s * 32 + q * 8];
            #pragma unroll
            for (int n = 0; n < 2; ++n) {
                #pragma unroll
                for (int tt = 0; tt < 4; ++tt) {
                    f16x8 bfrag = *(const f16x8*)&Bs[n][tt * 16 + lr][s * 32 + q * 8];
                    acc[n][tt] = __builtin_amdgcn_mfma_f32_16x16x32_f16(bfrag, afrag, acc[n][tt], 0, 0, 0);
                }
            }
        }

        // ---- epilogue: tanh(relu)+diag, float4 stores direct from acc ----
        // lane holds row wave*16+lr, cols q*4..q*4+3 of each 16-col block:
        // per store instr 16 rows x 64 B contiguous = 1 KB, fully coalesced.
        #pragma unroll
        for (int n = 0; n < 2; ++n) {
            if (n == 1 && !have2) break;     // WG-uniform skip (dup tile)
            const int tjn = n ? tj1 : tj0;
            const bool diagT = (ti == tjn);
            const int r_loc = wave * 16 + lr;
            float* dst = out + (size_t)b * M_NODES * M_NODES
                             + (size_t)(ti * TILE + r_loc) * M_NODES
                             + (size_t)(tjn * TILE + q * 4);
            #pragma unroll
            for (int tt = 0; tt < 4; ++tt) {
                const int c_loc = tt * 16 + q * 4;
                float4 o;
                float* po = &o.x;
                #pragma unroll
                for (int i = 0; i < 4; ++i) {
                    float v = tanh_relu(acc[n][tt][i]);
                    if (diagT && (r_loc == c_loc + i)) v += 0.5f;
                    po[i] = v;
                }
                *(float4*)(dst + tt * 16) = o;
            }
        }

        if (!more) break;
        t = tn;
    }
}

extern "C" void kernel_launch(void* const* d_in, const int* in_sizes, int n_in,
                              void* d_out, int out_size, void* d_ws, size_t ws_size,
                              hipStream_t stream) {
    const float* sp = (const float*)d_in[0];   // [16, 2048, 64] fp32
    const float* tp = (const float*)d_in[1];   // [16, 64, 64]   fp32
    float* out = (float*)d_out;                // [16, 2112, 2112] fp32

    dim3 grid(TOTAL_WGS);                      // 768 persistent WGs
    dim3 block(256);
    hipLaunchKernelGGL(gram_tanh_mfma, grid, block, 0, stream, sp, tp, out);
}

// Round 6
// 301.733 us; speedup vs baseline: 1.0005x; 1.0003x over previous
//
#include <hip/hip_runtime.h>
#include <hip/hip_fp16.h>

// adj[b] = tanh(relu(E_b @ E_b^T)) + 0.5*I
// E_b = concat(spatial[b] (2048x64), temporal[b] (64x64)) fp32 -> fp16 MFMA,
// fp32 accumulate. Output: [16, 2112, 2112] fp32.
// R12 = R11 (768 persistent WGs, 3/CU, XCD-partitioned, reg-prefetch) with
// ONE change: raw s_barrier + counted waits instead of __syncthreads.
// __syncthreads emits s_waitcnt vmcnt(0), which DRAINS OUTSTANDING STORES at
// every tile boundary; the kernel is HBM-write-bound (285 MB out), so the L2
// write path is congested and each barrier exposed ~10K cyc of store drain
// per round (~50-60 us total = the gap between the 50 us overlapped model
// and measured ~105 us). Raw-barrier scheme (m201-verified pattern):
//   top barrier:   NO waitcnt (ds_reads of prev tile already CONSUMED by
//                  MFMA before the wave arrives; stores stay in flight)
//   post-staging:  s_waitcnt lgkmcnt(0) only, then s_barrier
// vmem FIFO = [loads t+1][stores t], so consuming prefetch regs next iter
// needs only a counted vmcnt (<=8 stores outstanding), never vmcnt(0).
// Stores of tile t retire under tile t+1's staging/MFMA/epilogue.

#define B_BATCH   16
#define N_SPATIAL 2048
#define T_TEMP    64
#define M_NODES   2112     // 33 * 64
#define D_FEAT    64
#define TILE      64
#define LDSK      72       // fp16 k-stride (+8 pad)

#define GROUPS_PER_STRIP 17
#define TILES_PER_BATCH  (33 * GROUPS_PER_STRIP)   // 561
#define TILES_PER_XCD    (2 * TILES_PER_BATCH)     // 1122
#define WGS_PER_XCD      96
#define TOTAL_WGS        (WGS_PER_XCD * 8)         // 768 = 3 per CU

typedef _Float16 f16x8 __attribute__((ext_vector_type(8)));
typedef float    f32x4 __attribute__((ext_vector_type(4)));

__device__ __forceinline__ f16x8 cvt2v(float4 a, float4 c) {
    f16x8 h;
    h[0] = (_Float16)a.x; h[1] = (_Float16)a.y;
    h[2] = (_Float16)a.z; h[3] = (_Float16)a.w;
    h[4] = (_Float16)c.x; h[5] = (_Float16)c.y;
    h[6] = (_Float16)c.z; h[7] = (_Float16)c.w;
    return h;
}

__device__ __forceinline__ float tanh_relu(float x) {
    x = fmaxf(x, 0.f);
    // tanh(x), x>=0: 1 - 2/(e^{2x}+1); exp->inf saturates to 1
    float e = __expf(2.f * x);
    return 1.f - 2.f * __builtin_amdgcn_rcpf(e + 1.f);
}

// tile index t (0..1121) -> per-thread staging pointers (row/kb fixed)
__device__ __forceinline__ void tile_ptrs(int t, int xcd, int row, int kb,
                                          const float* __restrict__ sp,
                                          const float* __restrict__ tp,
                                          const float4*& pa,
                                          const float4*& pb0,
                                          const float4*& pb1)
{
    const int bo  = (t >= TILES_PER_BATCH) ? 1 : 0;
    const int rr  = t - bo * TILES_PER_BATCH;
    const int ti  = rr / GROUPS_PER_STRIP;          // 0..32
    const int g   = rr - ti * GROUPS_PER_STRIP;     // 0..16
    const int b   = 2 * xcd + bo;
    const int tj0 = 2 * g;
    const int tj1 = (tj0 + 1 < 33) ? tj0 + 1 : 32;  // clamp (dup on g==16)
    const float* srcA = (ti < 32)
        ? sp + ((size_t)b * N_SPATIAL + (size_t)ti * TILE) * D_FEAT
        : tp + (size_t)b * T_TEMP * D_FEAT;
    const float* srcB0 = (tj0 < 32)
        ? sp + ((size_t)b * N_SPATIAL + (size_t)tj0 * TILE) * D_FEAT
        : tp + (size_t)b * T_TEMP * D_FEAT;
    const float* srcB1 = (tj1 < 32)
        ? sp + ((size_t)b * N_SPATIAL + (size_t)tj1 * TILE) * D_FEAT
        : tp + (size_t)b * T_TEMP * D_FEAT;
    pa  = (const float4*)(srcA  + (size_t)row * D_FEAT + kb);
    pb0 = (const float4*)(srcB0 + (size_t)row * D_FEAT + kb);
    pb1 = (const float4*)(srcB1 + (size_t)row * D_FEAT + kb);
}

__global__ __launch_bounds__(256, 3)
void gram_tanh_mfma(const float* __restrict__ sp,
                    const float* __restrict__ tp,
                    float* __restrict__ out)
{
    const int lin = blockIdx.x;
    const int xcd = lin & 7;                 // round-robin XCD dispatch
    const int w   = lin >> 3;                // 0..95 within XCD

    __shared__ __align__(16) _Float16 As[TILE][LDSK];       //  9216 B
    __shared__ __align__(16) _Float16 Bs[2][TILE][LDSK];    // 18432 B -> 27648 B

    const int tid  = threadIdx.x;
    const int row  = tid >> 2;               // staging row 0..63
    const int kb   = (tid & 3) * 16;         // staging k base
    const int wave = tid >> 6;
    const int lane = tid & 63;
    const int lr   = lane & 15;              // output row within 16-slice
    const int q    = lane >> 4;              // output col quad

    // ---- prologue: prefetch tile w into registers ----
    int t = w;
    float4 ra[4], rb0[4], rb1[4];
    {
        const float4 *pa, *pb0, *pb1;
        tile_ptrs(t, xcd, row, kb, sp, tp, pa, pb0, pb1);
        #pragma unroll
        for (int i = 0; i < 4; ++i) { ra[i] = pa[i]; rb0[i] = pb0[i]; rb1[i] = pb1[i]; }
    }

    for (;;) {
        // ---- decode current tile for compute ----
        const int bo  = (t >= TILES_PER_BATCH) ? 1 : 0;
        const int rr  = t - bo * TILES_PER_BATCH;
        const int ti  = rr / GROUPS_PER_STRIP;
        const int g   = rr - ti * GROUPS_PER_STRIP;
        const int b   = 2 * xcd + bo;
        const int tj0 = 2 * g;
        const bool have2 = (tj0 + 1 < 33);
        const int tj1 = have2 ? tj0 + 1 : 32;

        // ---- RAW barrier, NO vmem drain: every wave arriving here has
        // already consumed its ds_reads of the previous tile (MFMA inputs),
        // so LDS overwrite is safe; epilogue stores stay in flight. ----
        asm volatile("" ::: "memory");
        __builtin_amdgcn_s_barrier();
        asm volatile("" ::: "memory");

        // ---- regs -> LDS (convert fp32->fp16); consuming ra/rb waits on
        // the prefetch loads with a COUNTED vmcnt (stores sit behind them
        // in the vmem FIFO and need not drain). ----
        *(f16x8*)&As[row][kb]        = cvt2v(ra[0],  ra[1]);
        *(f16x8*)&As[row][kb + 8]    = cvt2v(ra[2],  ra[3]);
        *(f16x8*)&Bs[0][row][kb]     = cvt2v(rb0[0], rb0[1]);
        *(f16x8*)&Bs[0][row][kb + 8] = cvt2v(rb0[2], rb0[3]);
        *(f16x8*)&Bs[1][row][kb]     = cvt2v(rb1[0], rb1[1]);
        *(f16x8*)&Bs[1][row][kb + 8] = cvt2v(rb1[2], rb1[3]);

        // ---- ds_writes visible to the WG, then raw barrier ----
        asm volatile("s_waitcnt lgkmcnt(0)" ::: "memory");
        __builtin_amdgcn_s_barrier();
        asm volatile("" ::: "memory");

        // ---- issue NEXT tile's loads; latency hides under MFMA+epilogue ----
        const int tn = t + WGS_PER_XCD;
        const bool more = (tn < TILES_PER_XCD);
        if (more) {
            const float4 *pa, *pb0, *pb1;
            tile_ptrs(tn, xcd, row, kb, sp, tp, pa, pb0, pb1);
            #pragma unroll
            for (int i = 0; i < 4; ++i) { ra[i] = pa[i]; rb0[i] = pb0[i]; rb1[i] = pb1[i]; }
        }

        // ---- MFMA (swapped operands -> row-major C layout in acc) ----
        f32x4 acc[2][4];
        #pragma unroll
        for (int n = 0; n < 2; ++n)
            #pragma unroll
            for (int tt = 0; tt < 4; ++tt) acc[n][tt] = (f32x4){0.f, 0.f, 0.f, 0.f};

        #pragma unroll
        for (int s = 0; s < 2; ++s) {        // K = 64 = 2 x 32
            f16x8 afrag = *(const f16x8*)&As[wave * 16 + lr][s * 32 + q * 8];
            #pragma unroll
            for (int n = 0; n < 2; ++n) {
                #pragma unroll
                for (int tt = 0; tt < 4; ++tt) {
                    f16x8 bfrag = *(const f16x8*)&Bs[n][tt * 16 + lr][s * 32 + q * 8];
                    acc[n][tt] = __builtin_amdgcn_mfma_f32_16x16x32_f16(bfrag, afrag, acc[n][tt], 0, 0, 0);
                }
            }
        }

        // ---- epilogue: tanh(relu)+diag, float4 stores direct from acc ----
        // lane holds row wave*16+lr, cols q*4..q*4+3 of each 16-col block:
        // per store instr 16 rows x 64 B contiguous = 1 KB, fully coalesced.
        #pragma unroll
        for (int n = 0; n < 2; ++n) {
            if (n == 1 && !have2) break;     // WG-uniform skip (dup tile)
            const int tjn = n ? tj1 : tj0;
            const bool diagT = (ti == tjn);
            const int r_loc = wave * 16 + lr;
            float* dst = out + (size_t)b * M_NODES * M_NODES
                             + (size_t)(ti * TILE + r_loc) * M_NODES
                             + (size_t)(tjn * TILE + q * 4);
            #pragma unroll
            for (int tt = 0; tt < 4; ++tt) {
                const int c_loc = tt * 16 + q * 4;
                float4 o;
                float* po = &o.x;
                #pragma unroll
                for (int i = 0; i < 4; ++i) {
                    float v = tanh_relu(acc[n][tt][i]);
                    if (diagT && (r_loc == c_loc + i)) v += 0.5f;
                    po[i] = v;
                }
                *(float4*)(dst + tt * 16) = o;
            }
        }

        if (!more) break;
        t = tn;
    }
}

extern "C" void kernel_launch(void* const* d_in, const int* in_sizes, int n_in,
                              void* d_out, int out_size, void* d_ws, size_t ws_size,
                              hipStream_t stream) {
    const float* sp = (const float*)d_in[0];   // [16, 2048, 64] fp32
    const float* tp = (const float*)d_in[1];   // [16, 64, 64]   fp32
    float* out = (float*)d_out;                // [16, 2112, 2112] fp32

    dim3 grid(TOTAL_WGS);                      // 768 persistent WGs
    dim3 block(256);
    hipLaunchKernelGGL(gram_tanh_mfma, grid, block, 0, stream, sp, tp, out);
}

// Round 7
// 278.783 us; speedup vs baseline: 1.0829x; 1.0823x over previous
//
#include <hip/hip_runtime.h>
#include <hip/hip_fp16.h>

// adj[b] = tanh(relu(E_b @ E_b^T)) + 0.5*I
// E_b = concat(spatial[b] (2048x64), temporal[b] (64x64)) fp32 -> fp16 MFMA,
// fp32 accumulate. Output: [16, 2112, 2112] fp32.
// R13 = R6 (best measured: 279.5) with ONE change: full-cache-line stores.
// R6/R9 stored 16 rows x 64 B per instruction (4 lanes/row) -- every store
// is a HALF-LINE. If L2 write-allocates on partial-line writes it must
// fetch each output line from HBM first (hidden 285 MB read = the gap
// between the 45 us write floor and the measured ~105 us kernel).
// New store: 8 lanes/row -> 8 rows x 128 B per instruction, every store
// covers complete 128-B lines (row base tjn*256B, halves at +0/+128B).
// Same instruction count (4 float4 stores/thread/sub-tile), same bytes.
// Everything else byte-identical to R6: 64x128 tile per WG, one barrier,
// wave-private Ct transpose, XCD-partitioned tile order.

#define B_BATCH   16
#define N_SPATIAL 2048
#define T_TEMP    64
#define M_NODES   2112     // 33 * 64
#define D_FEAT    64
#define TILE      64
#define LDSK      72       // fp16 k-stride (+8 pad)
#define CSTR      68       // fp32 epilogue tile stride (+4 pad)

// per batch: 33 ti strips x 17 tj-groups (16 groups of 2 tiles + 1 of 1)
#define GROUPS_PER_STRIP 17
#define WGS_PER_BATCH    (33 * GROUPS_PER_STRIP)   // 561
#define TOTAL_WGS        (WGS_PER_BATCH * B_BATCH) // 8976 = 8 * 1122
#define WGS_PER_XCD      (TOTAL_WGS / 8)           // 1122 = 2 batches

typedef _Float16 f16x8 __attribute__((ext_vector_type(8)));
typedef float    f32x4 __attribute__((ext_vector_type(4)));

__device__ __forceinline__ f16x8 cvt2(const float4* p) {
    float4 a = p[0], c = p[1];
    f16x8 h;
    h[0] = (_Float16)a.x; h[1] = (_Float16)a.y;
    h[2] = (_Float16)a.z; h[3] = (_Float16)a.w;
    h[4] = (_Float16)c.x; h[5] = (_Float16)c.y;
    h[6] = (_Float16)c.z; h[7] = (_Float16)c.w;
    return h;
}

__global__ __launch_bounds__(256, 3)
void gram_tanh_mfma(const float* __restrict__ sp,
                    const float* __restrict__ tp,
                    float* __restrict__ out)
{
    // ---- XCD-aware decode: wg lin -> XCD (lin&7, round-robin dispatch);
    // XCD k owns local ids [0,1122) = batches 2k,2k+1, tj fastest.
    const int lin = blockIdx.x;
    const int xcd = lin & 7;
    const int l   = lin >> 3;            // 0..1121
    const int bo  = l / WGS_PER_BATCH;   // 0,1
    const int rr  = l - bo * WGS_PER_BATCH;
    const int ti  = rr / GROUPS_PER_STRIP;          // 0..32
    const int g   = rr - ti * GROUPS_PER_STRIP;     // 0..16
    const int b   = 2 * xcd + bo;
    const int tj0 = 2 * g;
    const bool have2 = (tj0 + 1 < 33);
    const int tj1 = have2 ? tj0 + 1 : 32;           // clamp (g==16 -> dup of tj0)

    __shared__ __align__(16) _Float16 As[TILE][LDSK];       //  9216 B
    __shared__ __align__(16) _Float16 Bs[2][TILE][LDSK];    // 18432 B
    __shared__ __align__(16) float    Ct[TILE][CSTR];       // 17408 B  -> 45056 B

    const int tid = threadIdx.x;

    // ---- stage + convert fp32 -> fp16: row = tid>>2, 16 consecutive k ----
    {
        const int row = tid >> 2;
        const int kb  = (tid & 3) * 16;
        const float* srcA = (ti < 32)
            ? sp + ((size_t)b * N_SPATIAL + (size_t)ti * TILE) * D_FEAT
            : tp + (size_t)b * T_TEMP * D_FEAT;
        const float* srcB0 = (tj0 < 32)
            ? sp + ((size_t)b * N_SPATIAL + (size_t)tj0 * TILE) * D_FEAT
            : tp + (size_t)b * T_TEMP * D_FEAT;
        const float* srcB1 = (tj1 < 32)
            ? sp + ((size_t)b * N_SPATIAL + (size_t)tj1 * TILE) * D_FEAT
            : tp + (size_t)b * T_TEMP * D_FEAT;
        const float4* pa  = (const float4*)(srcA  + (size_t)row * D_FEAT + kb);
        const float4* pb0 = (const float4*)(srcB0 + (size_t)row * D_FEAT + kb);
        const float4* pb1 = (const float4*)(srcB1 + (size_t)row * D_FEAT + kb);

        *(f16x8*)&As[row][kb]        = cvt2(pa);
        *(f16x8*)&As[row][kb + 8]    = cvt2(pa + 2);
        *(f16x8*)&Bs[0][row][kb]     = cvt2(pb0);
        *(f16x8*)&Bs[0][row][kb + 8] = cvt2(pb0 + 2);
        *(f16x8*)&Bs[1][row][kb]     = cvt2(pb1);
        *(f16x8*)&Bs[1][row][kb + 8] = cvt2(pb1 + 2);
    }
    __syncthreads();   // the ONLY barrier

    // ---- MFMA: wave w -> rows [16w,16w+16) x 2 sub-tiles of 64 cols ----
    const int wave = tid >> 6;
    const int lane = tid & 63;
    const int lr   = lane & 15;   // m (A) / n (B) within 16-tile
    const int q    = lane >> 4;   // quad -> k-slice / C row group

    f32x4 acc[2][4];
    #pragma unroll
    for (int n = 0; n < 2; ++n)
        #pragma unroll
        for (int tt = 0; tt < 4; ++tt) acc[n][tt] = (f32x4){0.f, 0.f, 0.f, 0.f};

    #pragma unroll
    for (int s = 0; s < 2; ++s) {                 // K = 64 = 2 x 32
        f16x8 afrag = *(const f16x8*)&As[wave * 16 + lr][s * 32 + q * 8];
        #pragma unroll
        for (int n = 0; n < 2; ++n) {
            #pragma unroll
            for (int tt = 0; tt < 4; ++tt) {
                f16x8 bfrag = *(const f16x8*)&Bs[n][tt * 16 + lr][s * 32 + q * 8];
                acc[n][tt] = __builtin_amdgcn_mfma_f32_16x16x32_f16(afrag, bfrag, acc[n][tt], 0, 0, 0);
            }
        }
    }

    // ---- per sub-tile: tanh(relu)+diag -> wave-private Ct slice -> stores ----
    // Wave w only touches Ct rows [16w,16w+16): no cross-wave sync needed.
    #pragma unroll
    for (int n = 0; n < 2; ++n) {
        if (n == 1 && !have2) break;              // wave-uniform skip (dup tile)
        const int tjn = n ? tj1 : tj0;
        const bool diagT = (ti == tjn);
        #pragma unroll
        for (int tt = 0; tt < 4; ++tt) {
            const int col = tt * 16 + lr;
            #pragma unroll
            for (int i = 0; i < 4; ++i) {
                const int row = wave * 16 + q * 4 + i;
                float x = fmaxf(acc[n][tt][i], 0.f);
                // tanh(x), x>=0: 1 - 2/(e^{2x}+1); exp->inf saturates to 1
                float e = __expf(2.f * x);
                float v = 1.f - 2.f * __builtin_amdgcn_rcpf(e + 1.f);
                if (diagT && (row == col)) v += 0.5f;
                Ct[row][col] = v;
            }
        }
        // in-wave LDS WAR/RAW ordering via lgkmcnt; no __syncthreads.
        // FULL-LINE stores: 8 lanes per row -> each global_store_dwordx4
        // covers 8 rows x 128 B complete cache lines (no partial-line
        // write-allocate RMW possible).
        const int rs = lane >> 3;                 // 0..7 row within half-slice
        #pragma unroll
        for (int rh = 0; rh < 2; ++rh) {
            const int r_loc = wave * 16 + rh * 8 + rs;
            float* dst = out + (size_t)b * M_NODES * M_NODES
                             + (size_t)(ti * TILE + r_loc) * M_NODES
                             + tjn * TILE;
            #pragma unroll
            for (int u = 0; u < 2; ++u) {
                const int c4 = (lane & 7) * 4 + 32 * u;   // float offset 0..60
                *(float4*)(dst + c4) = *(const float4*)&Ct[r_loc][c4];
            }
        }
    }
}

extern "C" void kernel_launch(void* const* d_in, const int* in_sizes, int n_in,
                              void* d_out, int out_size, void* d_ws, size_t ws_size,
                              hipStream_t stream) {
    const float* sp = (const float*)d_in[0];   // [16, 2048, 64] fp32
    const float* tp = (const float*)d_in[1];   // [16, 64, 64]   fp32
    float* out = (float*)d_out;                // [16, 2112, 2112] fp32

    dim3 grid(TOTAL_WGS);                      // 8976; kernel does XCD decode
    dim3 block(256);
    hipLaunchKernelGGL(gram_tanh_mfma, grid, block, 0, stream, sp, tp, out);
}